// Round 11
// baseline (146.443 us; speedup 1.0000x reference)
//
#include <hip/hip_runtime.h>
#include <hip/hip_bf16.h>
#include <math.h>

#define N_NODES 50000
#define N_EDGES 1600000
#define D_IN 128
#define D_OUT 32
#define ALPHA 0.2f

#define NB   256     // coarse buckets
#define RPB  196     // rows per bucket (256*196 = 50176 >= 50000)
#define CAP  8192    // record slots per bucket (mean ~6250, +24 sigma)
#define GST  16      // gcount stride in ints: one counter per 64B line
#define PT   4       // edges per thread in edge kernel
#define EBK  512     // edge kernel block size (8 waves)
#define EB   (PT * EBK)                     // 2048 edges per edge-block
#define NEB  ((N_EDGES + EB - 1) / EB)      // 782 edge blocks (~3.05/CU)
#define XNPB 64      // nodes per GEMM block (2 nodes/thread: W-reuse)
#define NXB  ((N_NODES + XNPB - 1) / XNPB)  // 782 GEMM blocks

// Monotone float<->int key (involution). Works with signed min/max.
__device__ __forceinline__ int enc_f(float x) {
    int i = __float_as_int(x);
    return i >= 0 ? i : (i ^ 0x7fffffff);
}
__device__ __forceinline__ float dec_f(int k) {
    return __int_as_float(k >= 0 ? k : (k ^ 0x7fffffff));
}
__device__ __forceinline__ unsigned short f2bf(float x) {
    __hip_bfloat16 h = __float2bfloat16(x);
    return *(unsigned short*)&h;
}
__device__ __forceinline__ float bf2f(unsigned short u) {
    return __uint_as_float((unsigned)u << 16);
}

// K1: GEMM X@W -> Xpb (bf16) with s0/s1 epilogue, 2 nodes per thread.
// v2: X read DIRECTLY from global (no LDS staging). The 8 lanes of a node
// read the same 16B chunk per kk -> hardware same-address broadcast (one
// transaction), and consecutive kk reuse each 128B line 8x via L1. LDS
// drops 50->16 KB (3 blocks/CU, 12 waves), one barrier less, X HBM traffic
// unchanged. Load index clamped for the last block's 48 over-range rows.
// Block 0 zeroes the padded gcount array (harness poisons workspace).
__global__ __launch_bounds__(256) void k_gemm(const float* __restrict__ X,
                                              const float* __restrict__ W,
                                              const float* __restrict__ a0,
                                              const float* __restrict__ a1,
                                              unsigned short* __restrict__ Xpb,
                                              float* __restrict__ s0,
                                              float* __restrict__ s1,
                                              int* __restrict__ gcount) {
    __shared__ float4 Wl4[1024];        // 16 KB
    const int tid = threadIdx.x;
    if (blockIdx.x == 0) {
        int4* g4 = (int4*)gcount;
#pragma unroll
        for (int i = 0; i < NB * GST / 4 / 256; ++i)
            g4[tid + 256 * i] = make_int4(0, 0, 0, 0);
    }
    {
        const float4* W4 = (const float4*)W;
#pragma unroll
        for (int i = 0; i < 4; ++i) Wl4[tid + 256 * i] = W4[tid + 256 * i];
    }
    __syncthreads();
    const int g = tid >> 3;  // node pair (0..31): nodes g and g+32
    const int l = tid & 7;   // lane -> dims [4l, 4l+4)
    const int nodeA = blockIdx.x * XNPB + g;
    const int nodeB = nodeA + 32;
    const float4* xr0 =
        (const float4*)X + (size_t)min(nodeA, N_NODES - 1) * (D_IN / 4);
    const float4* xr1 =
        (const float4*)X + (size_t)min(nodeB, N_NODES - 1) * (D_IN / 4);
    float axA = 0.f, ayA = 0.f, azA = 0.f, awA = 0.f;
    float axB = 0.f, ayB = 0.f, azB = 0.f, awB = 0.f;
#pragma unroll 4
    for (int kk = 0; kk < D_IN / 4; ++kk) {
        const float4 xa = xr0[kk];
        const float4 xb = xr1[kk];
        const float4 w0 = Wl4[(4 * kk + 0) * 8 + l];
        const float4 w1 = Wl4[(4 * kk + 1) * 8 + l];
        const float4 w2 = Wl4[(4 * kk + 2) * 8 + l];
        const float4 w3 = Wl4[(4 * kk + 3) * 8 + l];
        axA += xa.x * w0.x + xa.y * w1.x + xa.z * w2.x + xa.w * w3.x;
        ayA += xa.x * w0.y + xa.y * w1.y + xa.z * w2.y + xa.w * w3.y;
        azA += xa.x * w0.z + xa.y * w1.z + xa.z * w2.z + xa.w * w3.z;
        awA += xa.x * w0.w + xa.y * w1.w + xa.z * w2.w + xa.w * w3.w;
        axB += xb.x * w0.x + xb.y * w1.x + xb.z * w2.x + xb.w * w3.x;
        ayB += xb.x * w0.y + xb.y * w1.y + xb.z * w2.y + xb.w * w3.y;
        azB += xb.x * w0.z + xb.y * w1.z + xb.z * w2.z + xb.w * w3.z;
        awB += xb.x * w0.w + xb.y * w1.w + xb.z * w2.w + xb.w * w3.w;
    }
    const float4 av0 = ((const float4*)a0)[l];
    const float4 av1 = ((const float4*)a1)[l];
    {   // node A
        if (nodeA < N_NODES) {
            uint2 pk;
            pk.x = ((unsigned)f2bf(ayA) << 16) | f2bf(axA);
            pk.y = ((unsigned)f2bf(awA) << 16) | f2bf(azA);
            ((uint2*)Xpb)[(size_t)nodeA * 8 + l] = pk;
            float v0 = axA * av0.x + ayA * av0.y + azA * av0.z + awA * av0.w;
            float v1 = axA * av1.x + ayA * av1.y + azA * av1.z + awA * av1.w;
#pragma unroll
            for (int m = 4; m >= 1; m >>= 1) {
                v0 += __shfl_xor(v0, m);
                v1 += __shfl_xor(v1, m);
            }
            if (l == 0) { s0[nodeA] = v0; s1[nodeA] = v1; }
        }
    }
    {   // node B
        if (nodeB < N_NODES) {
            uint2 pk;
            pk.x = ((unsigned)f2bf(ayB) << 16) | f2bf(axB);
            pk.y = ((unsigned)f2bf(awB) << 16) | f2bf(azB);
            ((uint2*)Xpb)[(size_t)nodeB * 8 + l] = pk;
            float v0 = axB * av0.x + ayB * av0.y + azB * av0.z + awB * av0.w;
            float v1 = axB * av1.x + ayB * av1.y + azB * av1.z + awB * av1.w;
#pragma unroll
            for (int m = 4; m >= 1; m >>= 1) {
                v0 += __shfl_xor(v0, m);
                v1 += __shfl_xor(v1, m);
            }
            if (l == 0) { s0[nodeB] = v0; s1[nodeB] = v1; }
        }
    }
}

// K2: edge pass v9 — LDS-staged counting sort + coalesced write-out at
// EB=2048 (782 blocks x 512 threads, PT=4). vs R10 (EB=4096, 391 blocks):
// per-thread dependent chains halve (4 gathers / 4 LDS-atomic links),
// staging LDS 36->20 KB (3 blocks/CU, 24 waves/CU), grid granularity
// 3.05 blocks/CU. Density 8 rec/bkt/blk is still line-safe because the
// staged copy-out makes successive blocks' runs CONTIGUOUS in each
// bucket's global region (sequential gbase claims -> L2 line merge).
// hist/scan sections run on the first 4 waves (tid<256).
__global__ __launch_bounds__(512) void k_edge(const int* __restrict__ row,
                                              const int* __restrict__ col,
                                              const float* __restrict__ s0,
                                              const float* __restrict__ s1,
                                              int* __restrict__ gcount,
                                              int2* __restrict__ mm,
                                              uint2* __restrict__ gEdges) {
    __shared__ uint2 rec[EB];       // 16 KB staging
    __shared__ int hist[NB];        // 1 KB
    __shared__ int off[NB + 1];     // 1 KB: staging layout
    __shared__ int lcur[NB];        // 1 KB: staging cursors
    __shared__ int gbase[NB];       // 1 KB: claimed global bases
    __shared__ int wse[4];
    __shared__ int smn[8], smx[8];
    const int tid = threadIdx.x;
    if (tid < NB) hist[tid] = 0;
    __syncthreads();
    const int base = blockIdx.x * EB;
    unsigned px[PT];  // (b:8 | lr:8 | col:16)
    float    fa[PT];  // leaky-relu'd score
    int cnt = 0;
    int kmin = 0x7fffffff, kmax = 0x80000000;
    if (base + EB <= N_EDGES) {   // full block: one int4 per stream
        const int4 r4 = ((const int4*)(row + base))[tid];
        const int4 c4 = ((const int4*)(col + base))[tid];
        const int rr[4] = {r4.x, r4.y, r4.z, r4.w};
        const int cc[4] = {c4.x, c4.y, c4.z, c4.w};
#pragma unroll
        for (int j = 0; j < 4; ++j) {
            const int r = rr[j];
            const int c = cc[j];
            float a = s0[r] + s1[c];
            a = a > 0.f ? a : ALPHA * a;
            const int k = enc_f(a);
            kmin = min(kmin, k);
            kmax = max(kmax, k);
            const unsigned b = (unsigned)r / RPB;
            const unsigned lr = (unsigned)r - b * RPB;
            px[cnt] = (b << 24) | (lr << 16) | (unsigned)c;
            fa[cnt] = a;
            ++cnt;
            atomicAdd(&hist[b], 1);
        }
    } else {                      // tail block: scalar guarded
#pragma unroll
        for (int i = 0; i < PT; ++i) {
            const int e = base + i * EBK + tid;
            if (e >= N_EDGES) break;
            const int r = row[e];
            const int c = col[e];
            float a = s0[r] + s1[c];
            a = a > 0.f ? a : ALPHA * a;
            const int k = enc_f(a);
            kmin = min(kmin, k);
            kmax = max(kmax, k);
            const unsigned b = (unsigned)r / RPB;
            const unsigned lr = (unsigned)r - b * RPB;
            px[cnt] = (b << 24) | (lr << 16) | (unsigned)c;
            fa[cnt] = a;
            ++cnt;
            atomicAdd(&hist[b], 1);
        }
    }
    __syncthreads();
    // claim one contiguous global range per touched bucket (overlaps scan);
    // parallel exclusive scan of hist on the first 4 waves
    int h = 0, inc = 0;
    if (tid < NB) {
        h = hist[tid];
        gbase[tid] = h > 0 ? atomicAdd(&gcount[tid << 4], h) : 0;
        inc = h;
        const int lane = tid & 63;
#pragma unroll
        for (int d = 1; d < 64; d <<= 1) {
            const int u = __shfl_up(inc, d);
            if (lane >= d) inc += u;
        }
        if (lane == 63) wse[tid >> 6] = inc;
    }
    __syncthreads();
    if (tid < NB) {
        int addp = 0;
        const int wv = tid >> 6;
#pragma unroll
        for (int w = 0; w < 4; ++w)
            if (w < wv) addp += wse[w];
        const int exc = inc - h + addp;
        off[tid] = exc;
        lcur[tid] = exc;
        if (tid == NB - 1) off[NB] = inc + addp;
    }
    __syncthreads();
    // counting-sort scatter into LDS staging (bucket-contiguous)
    for (int j = 0; j < cnt; ++j) {
        const unsigned b = px[j] >> 24;
        const int p = atomicAdd(&lcur[b], 1);
        rec[p] = make_uint2(px[j], (unsigned)__float_as_int(fa[j]));
    }
    __syncthreads();
    // coalesced copy-out: consecutive i -> same-bucket run -> burst stores
    const int total = off[NB];
    for (int i = tid; i < total; i += EBK) {
        const uint2 e = rec[i];
        const unsigned b = e.x >> 24;
        const int pos = gbase[b] + (i - off[b]);
        if (pos < CAP) gEdges[(size_t)b * CAP + pos] = e;
    }
    // epilogue: block min/max -> private slot (no contended atomics)
#pragma unroll
    for (int m = 32; m >= 1; m >>= 1) {
        kmin = min(kmin, __shfl_xor(kmin, m));
        kmax = max(kmax, __shfl_xor(kmax, m));
    }
    const int wave = tid >> 6;
    if ((tid & 63) == 0) { smn[wave] = kmin; smx[wave] = kmax; }
    __syncthreads();
    if (tid == 0) {
#pragma unroll
        for (int w = 1; w < 8; ++w) {
            kmin = min(kmin, smn[w]);
            kmax = max(kmax, smx[w]);
        }
        mm[blockIdx.x] = make_int2(kmin, kmax);
    }
}

// K3: one 1024-thread block per FULL coarse bucket (256 blocks, ~51 KB LDS,
// single scan). Parallel 4-wave shfl scan for the 196-bin prefix.
// prologue: reduce the 782-entry per-edge-block minmax table;
// pass 1:   LDS histogram of the bucket's 196 rows;
// pass 2:   counting-sort scatter {col:u16, exp(minmaxnorm(score))};
// rows:     64 row-processors x 16 lanes (2 bf16 dims per lane via one u32
//           load), 4-way unrolled register accumulators, float2 out.
__global__ __launch_bounds__(1024, 1) void k_bucket(const int* __restrict__ gcount,
                                                    const uint2* __restrict__ gEdges,
                                                    const unsigned short* __restrict__ Xpb,
                                                    const int2* __restrict__ mm,
                                                    float* __restrict__ out) {
    __shared__ unsigned short scol[CAP]; // 16 KB
    __shared__ float swt[CAP];           // 32 KB
    __shared__ int off[RPB + 1];
    __shared__ int cur[RPB];
    __shared__ int wsc[4];
    __shared__ int rmn[16], rmx[16];
    __shared__ float s_mn, s_inv;
    const int b = blockIdx.x;
    const int t = threadIdx.x;
    const int cnt = min(gcount[b << 4], CAP);   // padded gcount
    const uint2* eb = gEdges + (size_t)b * CAP;

    // prologue: global min/max from the per-edge-block table
    int kmn = 0x7fffffff, kmx = 0x80000000;
    for (int i = t; i < NEB; i += 1024) {
        const int2 v = mm[i];
        kmn = min(kmn, v.x);
        kmx = max(kmx, v.y);
    }
#pragma unroll
    for (int m = 32; m >= 1; m >>= 1) {
        kmn = min(kmn, __shfl_xor(kmn, m));
        kmx = max(kmx, __shfl_xor(kmx, m));
    }
    if ((t & 63) == 0) { rmn[t >> 6] = kmn; rmx[t >> 6] = kmx; }
    if (t < RPB) cur[t] = 0;  // temp hist (same barrier covers this)
    __syncthreads();
    if (t == 0) {
#pragma unroll
        for (int w = 1; w < 16; ++w) {
            kmn = min(kmn, rmn[w]);
            kmx = max(kmx, rmx[w]);
        }
        const float mn = dec_f(kmn);
        const float mx = dec_f(kmx);
        s_mn = mn;
        s_inv = 1.0f / (mx - mn);
    }
    // pass 1: histogram of the bucket's rows
    for (int i = t; i < cnt; i += 1024)
        atomicAdd(&cur[(eb[i].x >> 16) & 0xFFu], 1);
    __syncthreads();
    // parallel exclusive scan of cur[0..195] -> off (first 4 waves)
    int inc_s = 0, v_s = 0;
    if (t < 256) {
        v_s = (t < RPB) ? cur[t] : 0;
        inc_s = v_s;
        const int lane = t & 63;
#pragma unroll
        for (int d = 1; d < 64; d <<= 1) {
            const int u = __shfl_up(inc_s, d);
            if (lane >= d) inc_s += u;
        }
        if (lane == 63) wsc[t >> 6] = inc_s;
    }
    __syncthreads();
    if (t < 256) {
        int addp = 0;
        const int wv = t >> 6;
#pragma unroll
        for (int w = 0; w < 4; ++w)
            if (w < wv) addp += wsc[w];
        if (t < RPB) off[t] = inc_s - v_s + addp;
        if (t == 255) off[RPB] = inc_s + addp;
    }
    __syncthreads();
    if (t < RPB) cur[t] = off[t];
    __syncthreads();
    const float mn = s_mn;
    const float inv = s_inv;
    // pass 2: counting-sort scatter (exp computed once per edge)
    for (int i = t; i < cnt; i += 1024) {
        const uint2 e = eb[i];
        const int lr = (int)((e.x >> 16) & 0xFFu);
        const int p = atomicAdd(&cur[lr], 1);
        if (p < CAP) {
            scol[p] = (unsigned short)(e.x & 0xFFFFu);
            swt[p] = __expf((__int_as_float(e.y) - mn) * inv);
        }
    }
    __syncthreads();

    // row processing: 64 processors x 16 lanes, 2 dims/lane, 4-way unroll
    const int proc = t >> 4;  // 0..63
    const int d2 = t & 15;    // dims [2*d2, 2*d2+1]
    const unsigned* Xp32 = (const unsigned*)Xpb;
    for (int lr = proc; lr < RPB; lr += 64) {
        const int s = off[lr];
        const int e2 = off[lr + 1];
        float pa0 = 0.f, pa1 = 0.f, pa2 = 0.f, pa3 = 0.f;
        float pb0 = 0.f, pb1 = 0.f, pb2 = 0.f, pb3 = 0.f;
        float w0s = 0.f, w1s = 0.f, w2s = 0.f, w3s = 0.f;
        int i = s;
        for (; i + 3 < e2; i += 4) {
            const int c0 = scol[i];
            const int c1 = scol[i + 1];
            const int c2 = scol[i + 2];
            const int c3 = scol[i + 3];
            const float w0 = swt[i];
            const float w1 = swt[i + 1];
            const float w2 = swt[i + 2];
            const float w3 = swt[i + 3];
            const unsigned u0 = Xp32[(size_t)c0 * 16 + d2];
            const unsigned u1 = Xp32[(size_t)c1 * 16 + d2];
            const unsigned u2 = Xp32[(size_t)c2 * 16 + d2];
            const unsigned u3 = Xp32[(size_t)c3 * 16 + d2];
            pa0 += w0 * bf2f((unsigned short)(u0 & 0xFFFFu));
            pb0 += w0 * bf2f((unsigned short)(u0 >> 16));
            pa1 += w1 * bf2f((unsigned short)(u1 & 0xFFFFu));
            pb1 += w1 * bf2f((unsigned short)(u1 >> 16));
            pa2 += w2 * bf2f((unsigned short)(u2 & 0xFFFFu));
            pb2 += w2 * bf2f((unsigned short)(u2 >> 16));
            pa3 += w3 * bf2f((unsigned short)(u3 & 0xFFFFu));
            pb3 += w3 * bf2f((unsigned short)(u3 >> 16));
            w0s += w0; w1s += w1; w2s += w2; w3s += w3;
        }
        for (; i < e2; ++i) {
            const float w = swt[i];
            const unsigned u = Xp32[(size_t)scol[i] * 16 + d2];
            pa0 += w * bf2f((unsigned short)(u & 0xFFFFu));
            pb0 += w * bf2f((unsigned short)(u >> 16));
            w0s += w;
        }
        const int r = b * RPB + lr;
        if (r < N_NODES) {
            const float ws = w0s + w1s + w2s + w3s;
            float2 o;
            o.x = (pa0 + pa1 + pa2 + pa3) / ws;
            o.y = (pb0 + pb1 + pb2 + pb3) / ws;
            ((float2*)out)[(size_t)r * 16 + d2] = o;
        }
    }
}

extern "C" void kernel_launch(void* const* d_in, const int* in_sizes, int n_in,
                              void* d_out, int out_size, void* d_ws, size_t ws_size,
                              hipStream_t stream) {
    const float* X  = (const float*)d_in[0];
    const float* W  = (const float*)d_in[1];
    const float* a0 = (const float*)d_in[2];
    const float* a1 = (const float*)d_in[3];
    const int* row  = (const int*)d_in[4];
    const int* col  = (const int*)d_in[5];
    float* out = (float*)d_out;

    // Workspace layout (4B units):
    // [pad: 64][gcount padded: NB*GST = 4096][mm: 2048]
    // [s0: 50048][s1: 50048][Xpb: 800000 u32][gEdges: NB*CAP uint2] ~20.4 MB
    float* ws = (float*)d_ws;
    int*   gcount = (int*)ws + 64;
    int2*  mm = (int2*)((int*)ws + 64 + NB * GST);
    float* s0 = ws + 64 + NB * GST + 2048;
    float* s1 = s0 + 50048;
    unsigned short* Xpb = (unsigned short*)(s1 + 50048);
    uint2* gEdges = (uint2*)(s1 + 50048 + 800000);

    k_gemm<<<NXB, 256, 0, stream>>>(X, W, a0, a1, Xpb, s0, s1, gcount);
    k_edge<<<NEB, 512, 0, stream>>>(row, col, s0, s1, gcount, mm, gEdges);
    k_bucket<<<NB, 1024, 0, stream>>>(gcount, gEdges, Xpb, mm, out);
}

// Round 12
// 139.430 us; speedup vs baseline: 1.0503x; 1.0503x over previous
//
#include <hip/hip_runtime.h>
#include <hip/hip_bf16.h>
#include <math.h>

#define N_NODES 50000
#define N_EDGES 1600000
#define D_IN 128
#define D_OUT 32
#define ALPHA 0.2f

#define NB   256     // coarse buckets (density: EB/NB = 16 rec/bkt/blk)
#define RPB  196     // rows per bucket (256*196 = 50176 >= 50000)
#define CAP  8192    // record slots per bucket (mean ~6250, +24 sigma)
#define GST  16      // gcount stride in ints: one counter per 64B line
#define PT   8       // edges per thread in edge kernel
#define EBK  512     // edge kernel block size (8 waves: latency hiding)
#define EB   (PT * EBK)                     // 4096 edges per edge-block
#define NEB  ((N_EDGES + EB - 1) / EB)      // 391 edge blocks
#define XNPB 64      // nodes per GEMM block (2 nodes/thread: W-reuse)
#define NXB  ((N_NODES + XNPB - 1) / XNPB)  // 782 GEMM blocks

// Monotone float<->int key (involution). Works with signed min/max.
__device__ __forceinline__ int enc_f(float x) {
    int i = __float_as_int(x);
    return i >= 0 ? i : (i ^ 0x7fffffff);
}
__device__ __forceinline__ float dec_f(int k) {
    return __int_as_float(k >= 0 ? k : (k ^ 0x7fffffff));
}
__device__ __forceinline__ unsigned short f2bf(float x) {
    __hip_bfloat16 h = __float2bfloat16(x);
    return *(unsigned short*)&h;
}
__device__ __forceinline__ float bf2f(unsigned short u) {
    return __uint_as_float((unsigned)u << 16);
}

// K1: GEMM X@W -> Xpb (bf16) with s0/s1 epilogue, 2 nodes per thread.
// X read DIRECTLY from global (no LDS staging): the 8 lanes of a node read
// the same 16B chunk per kk -> same-address broadcast (one transaction),
// consecutive kk reuse each 128B line via L1. LDS 16 KB (W only).
// Block 0 zeroes the padded gcount array (harness poisons workspace).
__global__ __launch_bounds__(256) void k_gemm(const float* __restrict__ X,
                                              const float* __restrict__ W,
                                              const float* __restrict__ a0,
                                              const float* __restrict__ a1,
                                              unsigned short* __restrict__ Xpb,
                                              float* __restrict__ s0,
                                              float* __restrict__ s1,
                                              int* __restrict__ gcount) {
    __shared__ float4 Wl4[1024];        // 16 KB
    const int tid = threadIdx.x;
    if (blockIdx.x == 0) {
        int4* g4 = (int4*)gcount;
#pragma unroll
        for (int i = 0; i < NB * GST / 4 / 256; ++i)
            g4[tid + 256 * i] = make_int4(0, 0, 0, 0);
    }
    {
        const float4* W4 = (const float4*)W;
#pragma unroll
        for (int i = 0; i < 4; ++i) Wl4[tid + 256 * i] = W4[tid + 256 * i];
    }
    __syncthreads();
    const int g = tid >> 3;  // node pair (0..31): nodes g and g+32
    const int l = tid & 7;   // lane -> dims [4l, 4l+4)
    const int nodeA = blockIdx.x * XNPB + g;
    const int nodeB = nodeA + 32;
    const float4* xr0 =
        (const float4*)X + (size_t)min(nodeA, N_NODES - 1) * (D_IN / 4);
    const float4* xr1 =
        (const float4*)X + (size_t)min(nodeB, N_NODES - 1) * (D_IN / 4);
    float axA = 0.f, ayA = 0.f, azA = 0.f, awA = 0.f;
    float axB = 0.f, ayB = 0.f, azB = 0.f, awB = 0.f;
#pragma unroll 4
    for (int kk = 0; kk < D_IN / 4; ++kk) {
        const float4 xa = xr0[kk];
        const float4 xb = xr1[kk];
        const float4 w0 = Wl4[(4 * kk + 0) * 8 + l];
        const float4 w1 = Wl4[(4 * kk + 1) * 8 + l];
        const float4 w2 = Wl4[(4 * kk + 2) * 8 + l];
        const float4 w3 = Wl4[(4 * kk + 3) * 8 + l];
        axA += xa.x * w0.x + xa.y * w1.x + xa.z * w2.x + xa.w * w3.x;
        ayA += xa.x * w0.y + xa.y * w1.y + xa.z * w2.y + xa.w * w3.y;
        azA += xa.x * w0.z + xa.y * w1.z + xa.z * w2.z + xa.w * w3.z;
        awA += xa.x * w0.w + xa.y * w1.w + xa.z * w2.w + xa.w * w3.w;
        axB += xb.x * w0.x + xb.y * w1.x + xb.z * w2.x + xb.w * w3.x;
        ayB += xb.x * w0.y + xb.y * w1.y + xb.z * w2.y + xb.w * w3.y;
        azB += xb.x * w0.z + xb.y * w1.z + xb.z * w2.z + xb.w * w3.z;
        awB += xb.x * w0.w + xb.y * w1.w + xb.z * w2.w + xb.w * w3.w;
    }
    const float4 av0 = ((const float4*)a0)[l];
    const float4 av1 = ((const float4*)a1)[l];
    {   // node A
        if (nodeA < N_NODES) {
            uint2 pk;
            pk.x = ((unsigned)f2bf(ayA) << 16) | f2bf(axA);
            pk.y = ((unsigned)f2bf(awA) << 16) | f2bf(azA);
            ((uint2*)Xpb)[(size_t)nodeA * 8 + l] = pk;
            float v0 = axA * av0.x + ayA * av0.y + azA * av0.z + awA * av0.w;
            float v1 = axA * av1.x + ayA * av1.y + azA * av1.z + awA * av1.w;
#pragma unroll
            for (int m = 4; m >= 1; m >>= 1) {
                v0 += __shfl_xor(v0, m);
                v1 += __shfl_xor(v1, m);
            }
            if (l == 0) { s0[nodeA] = v0; s1[nodeA] = v1; }
        }
    }
    {   // node B
        if (nodeB < N_NODES) {
            uint2 pk;
            pk.x = ((unsigned)f2bf(ayB) << 16) | f2bf(axB);
            pk.y = ((unsigned)f2bf(awB) << 16) | f2bf(azB);
            ((uint2*)Xpb)[(size_t)nodeB * 8 + l] = pk;
            float v0 = axB * av0.x + ayB * av0.y + azB * av0.z + awB * av0.w;
            float v1 = axB * av1.x + ayB * av1.y + azB * av1.z + awB * av1.w;
#pragma unroll
            for (int m = 4; m >= 1; m >>= 1) {
                v0 += __shfl_xor(v0, m);
                v1 += __shfl_xor(v1, m);
            }
            if (l == 0) { s0[nodeB] = v0; s1[nodeB] = v1; }
        }
    }
}

// K2: edge pass — REVERTED to the R10-validated configuration: EB=4096,
// 512 threads (8 waves), PT=8, 391 blocks, 32 KB staging, density 16.
// R11's EB=2048 (density 8) regressed ~+6us: partial 64B-line runs from
// different CUs re-trigger the write-amplification the density law
// (R1/R4/R5/R6, monotone over 4 points) predicts. Density >= 16 is load-
// bearing; do not reduce EB/NB below 16.
// LDS-staged counting sort -> one global claim per touched bucket ->
// coalesced per-bucket-run copy-out. min/max -> private mm[bid] slot.
__global__ __launch_bounds__(512) void k_edge(const int* __restrict__ row,
                                              const int* __restrict__ col,
                                              const float* __restrict__ s0,
                                              const float* __restrict__ s1,
                                              int* __restrict__ gcount,
                                              int2* __restrict__ mm,
                                              uint2* __restrict__ gEdges) {
    __shared__ uint2 rec[EB];       // 32 KB staging
    __shared__ int hist[NB];        // 1 KB
    __shared__ int off[NB + 1];     // 1 KB: staging layout
    __shared__ int lcur[NB];        // 1 KB: staging cursors
    __shared__ int gbase[NB];       // 1 KB: claimed global bases
    __shared__ int wse[4];
    __shared__ int smn[8], smx[8];
    const int tid = threadIdx.x;
    if (tid < NB) hist[tid] = 0;
    __syncthreads();
    const int base = blockIdx.x * EB;
    unsigned px[PT];  // (b:8 | lr:8 | col:16)
    float    fa[PT];  // leaky-relu'd score
    int cnt = 0;
    int kmin = 0x7fffffff, kmax = 0x80000000;
    if (base + EB <= N_EDGES) {   // full block: int4 vector loads
#pragma unroll
        for (int i = 0; i < PT / 4; ++i) {
            const int4 r4 = ((const int4*)(row + base))[tid + i * EBK];
            const int4 c4 = ((const int4*)(col + base))[tid + i * EBK];
            const int rr[4] = {r4.x, r4.y, r4.z, r4.w};
            const int cc[4] = {c4.x, c4.y, c4.z, c4.w};
#pragma unroll
            for (int j = 0; j < 4; ++j) {
                const int r = rr[j];
                const int c = cc[j];
                float a = s0[r] + s1[c];
                a = a > 0.f ? a : ALPHA * a;
                const int k = enc_f(a);
                kmin = min(kmin, k);
                kmax = max(kmax, k);
                const unsigned b = (unsigned)r / RPB;
                const unsigned lr = (unsigned)r - b * RPB;
                px[cnt] = (b << 24) | (lr << 16) | (unsigned)c;
                fa[cnt] = a;
                ++cnt;
                atomicAdd(&hist[b], 1);
            }
        }
    } else {                      // tail block: scalar guarded
#pragma unroll
        for (int i = 0; i < PT; ++i) {
            const int e = base + i * EBK + tid;
            if (e >= N_EDGES) break;
            const int r = row[e];
            const int c = col[e];
            float a = s0[r] + s1[c];
            a = a > 0.f ? a : ALPHA * a;
            const int k = enc_f(a);
            kmin = min(kmin, k);
            kmax = max(kmax, k);
            const unsigned b = (unsigned)r / RPB;
            const unsigned lr = (unsigned)r - b * RPB;
            px[cnt] = (b << 24) | (lr << 16) | (unsigned)c;
            fa[cnt] = a;
            ++cnt;
            atomicAdd(&hist[b], 1);
        }
    }
    __syncthreads();
    // claim one contiguous global range per touched bucket (overlaps scan);
    // parallel exclusive scan of hist on the first 4 waves
    int h = 0, inc = 0;
    if (tid < NB) {
        h = hist[tid];
        gbase[tid] = h > 0 ? atomicAdd(&gcount[tid << 4], h) : 0;
        inc = h;
        const int lane = tid & 63;
#pragma unroll
        for (int d = 1; d < 64; d <<= 1) {
            const int u = __shfl_up(inc, d);
            if (lane >= d) inc += u;
        }
        if (lane == 63) wse[tid >> 6] = inc;
    }
    __syncthreads();
    if (tid < NB) {
        int addp = 0;
        const int wv = tid >> 6;
#pragma unroll
        for (int w = 0; w < 4; ++w)
            if (w < wv) addp += wse[w];
        const int exc = inc - h + addp;
        off[tid] = exc;
        lcur[tid] = exc;
        if (tid == NB - 1) off[NB] = inc + addp;
    }
    __syncthreads();
    // counting-sort scatter into LDS staging (bucket-contiguous)
    for (int j = 0; j < cnt; ++j) {
        const unsigned b = px[j] >> 24;
        const int p = atomicAdd(&lcur[b], 1);
        rec[p] = make_uint2(px[j], (unsigned)__float_as_int(fa[j]));
    }
    __syncthreads();
    // coalesced copy-out: consecutive i -> same-bucket run -> burst stores
    const int total = off[NB];
    for (int i = tid; i < total; i += EBK) {
        const uint2 e = rec[i];
        const unsigned b = e.x >> 24;
        const int pos = gbase[b] + (i - off[b]);
        if (pos < CAP) gEdges[(size_t)b * CAP + pos] = e;
    }
    // epilogue: block min/max -> private slot (no contended atomics)
#pragma unroll
    for (int m = 32; m >= 1; m >>= 1) {
        kmin = min(kmin, __shfl_xor(kmin, m));
        kmax = max(kmax, __shfl_xor(kmax, m));
    }
    const int wave = tid >> 6;
    if ((tid & 63) == 0) { smn[wave] = kmin; smx[wave] = kmax; }
    __syncthreads();
    if (tid == 0) {
#pragma unroll
        for (int w = 1; w < 8; ++w) {
            kmin = min(kmin, smn[w]);
            kmax = max(kmax, smx[w]);
        }
        mm[blockIdx.x] = make_int2(kmin, kmax);
    }
}

// K3: one 1024-thread block per FULL coarse bucket (256 blocks, ~51 KB LDS,
// single scan). Parallel 4-wave shfl scan for the 196-bin prefix.
// prologue: reduce the 391-entry per-edge-block minmax table;
// pass 1:   LDS histogram of the bucket's 196 rows;
// pass 2:   counting-sort scatter {col:u16, exp(minmaxnorm(score))};
// rows:     64 row-processors x 16 lanes (2 bf16 dims per lane via one u32
//           load), 4-way unrolled register accumulators, float2 out.
__global__ __launch_bounds__(1024, 1) void k_bucket(const int* __restrict__ gcount,
                                                    const uint2* __restrict__ gEdges,
                                                    const unsigned short* __restrict__ Xpb,
                                                    const int2* __restrict__ mm,
                                                    float* __restrict__ out) {
    __shared__ unsigned short scol[CAP]; // 16 KB
    __shared__ float swt[CAP];           // 32 KB
    __shared__ int off[RPB + 1];
    __shared__ int cur[RPB];
    __shared__ int wsc[4];
    __shared__ int rmn[16], rmx[16];
    __shared__ float s_mn, s_inv;
    const int b = blockIdx.x;
    const int t = threadIdx.x;
    const int cnt = min(gcount[b << 4], CAP);   // padded gcount
    const uint2* eb = gEdges + (size_t)b * CAP;

    // prologue: global min/max from the per-edge-block table
    int kmn = 0x7fffffff, kmx = 0x80000000;
    for (int i = t; i < NEB; i += 1024) {
        const int2 v = mm[i];
        kmn = min(kmn, v.x);
        kmx = max(kmx, v.y);
    }
#pragma unroll
    for (int m = 32; m >= 1; m >>= 1) {
        kmn = min(kmn, __shfl_xor(kmn, m));
        kmx = max(kmx, __shfl_xor(kmx, m));
    }
    if ((t & 63) == 0) { rmn[t >> 6] = kmn; rmx[t >> 6] = kmx; }
    if (t < RPB) cur[t] = 0;  // temp hist (same barrier covers this)
    __syncthreads();
    if (t == 0) {
#pragma unroll
        for (int w = 1; w < 16; ++w) {
            kmn = min(kmn, rmn[w]);
            kmx = max(kmx, rmx[w]);
        }
        const float mn = dec_f(kmn);
        const float mx = dec_f(kmx);
        s_mn = mn;
        s_inv = 1.0f / (mx - mn);
    }
    // pass 1: histogram of the bucket's rows
    for (int i = t; i < cnt; i += 1024)
        atomicAdd(&cur[(eb[i].x >> 16) & 0xFFu], 1);
    __syncthreads();
    // parallel exclusive scan of cur[0..195] -> off (first 4 waves)
    int inc_s = 0, v_s = 0;
    if (t < 256) {
        v_s = (t < RPB) ? cur[t] : 0;
        inc_s = v_s;
        const int lane = t & 63;
#pragma unroll
        for (int d = 1; d < 64; d <<= 1) {
            const int u = __shfl_up(inc_s, d);
            if (lane >= d) inc_s += u;
        }
        if (lane == 63) wsc[t >> 6] = inc_s;
    }
    __syncthreads();
    if (t < 256) {
        int addp = 0;
        const int wv = t >> 6;
#pragma unroll
        for (int w = 0; w < 4; ++w)
            if (w < wv) addp += wsc[w];
        if (t < RPB) off[t] = inc_s - v_s + addp;
        if (t == 255) off[RPB] = inc_s + addp;
    }
    __syncthreads();
    if (t < RPB) cur[t] = off[t];
    __syncthreads();
    const float mn = s_mn;
    const float inv = s_inv;
    // pass 2: counting-sort scatter (exp computed once per edge)
    for (int i = t; i < cnt; i += 1024) {
        const uint2 e = eb[i];
        const int lr = (int)((e.x >> 16) & 0xFFu);
        const int p = atomicAdd(&cur[lr], 1);
        if (p < CAP) {
            scol[p] = (unsigned short)(e.x & 0xFFFFu);
            swt[p] = __expf((__int_as_float(e.y) - mn) * inv);
        }
    }
    __syncthreads();

    // row processing: 64 processors x 16 lanes, 2 dims/lane, 4-way unroll
    const int proc = t >> 4;  // 0..63
    const int d2 = t & 15;    // dims [2*d2, 2*d2+1]
    const unsigned* Xp32 = (const unsigned*)Xpb;
    for (int lr = proc; lr < RPB; lr += 64) {
        const int s = off[lr];
        const int e2 = off[lr + 1];
        float pa0 = 0.f, pa1 = 0.f, pa2 = 0.f, pa3 = 0.f;
        float pb0 = 0.f, pb1 = 0.f, pb2 = 0.f, pb3 = 0.f;
        float w0s = 0.f, w1s = 0.f, w2s = 0.f, w3s = 0.f;
        int i = s;
        for (; i + 3 < e2; i += 4) {
            const int c0 = scol[i];
            const int c1 = scol[i + 1];
            const int c2 = scol[i + 2];
            const int c3 = scol[i + 3];
            const float w0 = swt[i];
            const float w1 = swt[i + 1];
            const float w2 = swt[i + 2];
            const float w3 = swt[i + 3];
            const unsigned u0 = Xp32[(size_t)c0 * 16 + d2];
            const unsigned u1 = Xp32[(size_t)c1 * 16 + d2];
            const unsigned u2 = Xp32[(size_t)c2 * 16 + d2];
            const unsigned u3 = Xp32[(size_t)c3 * 16 + d2];
            pa0 += w0 * bf2f((unsigned short)(u0 & 0xFFFFu));
            pb0 += w0 * bf2f((unsigned short)(u0 >> 16));
            pa1 += w1 * bf2f((unsigned short)(u1 & 0xFFFFu));
            pb1 += w1 * bf2f((unsigned short)(u1 >> 16));
            pa2 += w2 * bf2f((unsigned short)(u2 & 0xFFFFu));
            pb2 += w2 * bf2f((unsigned short)(u2 >> 16));
            pa3 += w3 * bf2f((unsigned short)(u3 & 0xFFFFu));
            pb3 += w3 * bf2f((unsigned short)(u3 >> 16));
            w0s += w0; w1s += w1; w2s += w2; w3s += w3;
        }
        for (; i < e2; ++i) {
            const float w = swt[i];
            const unsigned u = Xp32[(size_t)scol[i] * 16 + d2];
            pa0 += w * bf2f((unsigned short)(u & 0xFFFFu));
            pb0 += w * bf2f((unsigned short)(u >> 16));
            w0s += w;
        }
        const int r = b * RPB + lr;
        if (r < N_NODES) {
            const float ws = w0s + w1s + w2s + w3s;
            float2 o;
            o.x = (pa0 + pa1 + pa2 + pa3) / ws;
            o.y = (pb0 + pb1 + pb2 + pb3) / ws;
            ((float2*)out)[(size_t)r * 16 + d2] = o;
        }
    }
}

extern "C" void kernel_launch(void* const* d_in, const int* in_sizes, int n_in,
                              void* d_out, int out_size, void* d_ws, size_t ws_size,
                              hipStream_t stream) {
    const float* X  = (const float*)d_in[0];
    const float* W  = (const float*)d_in[1];
    const float* a0 = (const float*)d_in[2];
    const float* a1 = (const float*)d_in[3];
    const int* row  = (const int*)d_in[4];
    const int* col  = (const int*)d_in[5];
    float* out = (float*)d_out;

    // Workspace layout (4B units):
    // [pad: 64][gcount padded: NB*GST = 4096][mm: 2048]
    // [s0: 50048][s1: 50048][Xpb: 800000 u32][gEdges: NB*CAP uint2] ~20.4 MB
    float* ws = (float*)d_ws;
    int*   gcount = (int*)ws + 64;
    int2*  mm = (int2*)((int*)ws + 64 + NB * GST);
    float* s0 = ws + 64 + NB * GST + 2048;
    float* s1 = s0 + 50048;
    unsigned short* Xpb = (unsigned short*)(s1 + 50048);
    uint2* gEdges = (uint2*)(s1 + 50048 + 800000);

    k_gemm<<<NXB, 256, 0, stream>>>(X, W, a0, a1, Xpb, s0, s1, gcount);
    k_edge<<<NEB, 512, 0, stream>>>(row, col, s0, s1, gcount, mm, gEdges);
    k_bucket<<<NB, 1024, 0, stream>>>(gcount, gEdges, Xpb, mm, out);
}

// Round 13
// 139.110 us; speedup vs baseline: 1.0527x; 1.0023x over previous
//
#include <hip/hip_runtime.h>
#include <hip/hip_bf16.h>
#include <math.h>

#define N_NODES 50000
#define N_EDGES 1600000
#define D_IN 128
#define D_OUT 32
#define ALPHA 0.2f

#define NB   256     // coarse buckets (density: EB/NB = 16 rec/bkt/blk)
#define RPB  196     // rows per bucket (256*196 = 50176 >= 50000)
#define CAP  8192    // record slots per bucket (mean ~6250, +24 sigma)
#define GST  16      // gcount stride in ints: one counter per 64B line
#define PT   8       // edges per thread in edge kernel
#define EBK  512     // edge kernel block size (8 waves: latency hiding)
#define EB   (PT * EBK)                     // 4096 edges per edge-block
#define NEB  ((N_EDGES + EB - 1) / EB)      // 391 edge blocks
#define XNPB 64      // nodes per GEMM block (2 nodes/thread: W-reuse)
#define NXB  ((N_NODES + XNPB - 1) / XNPB)  // 782 GEMM blocks

// Monotone float<->int key (involution). Works with signed min/max.
__device__ __forceinline__ int enc_f(float x) {
    int i = __float_as_int(x);
    return i >= 0 ? i : (i ^ 0x7fffffff);
}
__device__ __forceinline__ float dec_f(int k) {
    return __int_as_float(k >= 0 ? k : (k ^ 0x7fffffff));
}
__device__ __forceinline__ unsigned short f2bf(float x) {
    __hip_bfloat16 h = __float2bfloat16(x);
    return *(unsigned short*)&h;
}
__device__ __forceinline__ float bf2f(unsigned short u) {
    return __uint_as_float((unsigned)u << 16);
}

// K1: GEMM X@W -> Xpb (bf16) with s0/s1 epilogue, 2 nodes per thread.
// X read DIRECTLY from global (no LDS staging): the 8 lanes of a node read
// the same 16B chunk per kk -> same-address broadcast (one transaction),
// consecutive kk reuse each 128B line via L1. LDS 16 KB (W only).
// Block 0 zeroes the padded gcount array (harness poisons workspace).
__global__ __launch_bounds__(256) void k_gemm(const float* __restrict__ X,
                                              const float* __restrict__ W,
                                              const float* __restrict__ a0,
                                              const float* __restrict__ a1,
                                              unsigned short* __restrict__ Xpb,
                                              float* __restrict__ s0,
                                              float* __restrict__ s1,
                                              int* __restrict__ gcount) {
    __shared__ float4 Wl4[1024];        // 16 KB
    const int tid = threadIdx.x;
    if (blockIdx.x == 0) {
        int4* g4 = (int4*)gcount;
#pragma unroll
        for (int i = 0; i < NB * GST / 4 / 256; ++i)
            g4[tid + 256 * i] = make_int4(0, 0, 0, 0);
    }
    {
        const float4* W4 = (const float4*)W;
#pragma unroll
        for (int i = 0; i < 4; ++i) Wl4[tid + 256 * i] = W4[tid + 256 * i];
    }
    __syncthreads();
    const int g = tid >> 3;  // node pair (0..31): nodes g and g+32
    const int l = tid & 7;   // lane -> dims [4l, 4l+4)
    const int nodeA = blockIdx.x * XNPB + g;
    const int nodeB = nodeA + 32;
    const float4* xr0 =
        (const float4*)X + (size_t)min(nodeA, N_NODES - 1) * (D_IN / 4);
    const float4* xr1 =
        (const float4*)X + (size_t)min(nodeB, N_NODES - 1) * (D_IN / 4);
    float axA = 0.f, ayA = 0.f, azA = 0.f, awA = 0.f;
    float axB = 0.f, ayB = 0.f, azB = 0.f, awB = 0.f;
#pragma unroll 4
    for (int kk = 0; kk < D_IN / 4; ++kk) {
        const float4 xa = xr0[kk];
        const float4 xb = xr1[kk];
        const float4 w0 = Wl4[(4 * kk + 0) * 8 + l];
        const float4 w1 = Wl4[(4 * kk + 1) * 8 + l];
        const float4 w2 = Wl4[(4 * kk + 2) * 8 + l];
        const float4 w3 = Wl4[(4 * kk + 3) * 8 + l];
        axA += xa.x * w0.x + xa.y * w1.x + xa.z * w2.x + xa.w * w3.x;
        ayA += xa.x * w0.y + xa.y * w1.y + xa.z * w2.y + xa.w * w3.y;
        azA += xa.x * w0.z + xa.y * w1.z + xa.z * w2.z + xa.w * w3.z;
        awA += xa.x * w0.w + xa.y * w1.w + xa.z * w2.w + xa.w * w3.w;
        axB += xb.x * w0.x + xb.y * w1.x + xb.z * w2.x + xb.w * w3.x;
        ayB += xb.x * w0.y + xb.y * w1.y + xb.z * w2.y + xb.w * w3.y;
        azB += xb.x * w0.z + xb.y * w1.z + xb.z * w2.z + xb.w * w3.z;
        awB += xb.x * w0.w + xb.y * w1.w + xb.z * w2.w + xb.w * w3.w;
    }
    const float4 av0 = ((const float4*)a0)[l];
    const float4 av1 = ((const float4*)a1)[l];
    {   // node A
        if (nodeA < N_NODES) {
            uint2 pk;
            pk.x = ((unsigned)f2bf(ayA) << 16) | f2bf(axA);
            pk.y = ((unsigned)f2bf(awA) << 16) | f2bf(azA);
            ((uint2*)Xpb)[(size_t)nodeA * 8 + l] = pk;
            float v0 = axA * av0.x + ayA * av0.y + azA * av0.z + awA * av0.w;
            float v1 = axA * av1.x + ayA * av1.y + azA * av1.z + awA * av1.w;
#pragma unroll
            for (int m = 4; m >= 1; m >>= 1) {
                v0 += __shfl_xor(v0, m);
                v1 += __shfl_xor(v1, m);
            }
            if (l == 0) { s0[nodeA] = v0; s1[nodeA] = v1; }
        }
    }
    {   // node B
        if (nodeB < N_NODES) {
            uint2 pk;
            pk.x = ((unsigned)f2bf(ayB) << 16) | f2bf(axB);
            pk.y = ((unsigned)f2bf(awB) << 16) | f2bf(azB);
            ((uint2*)Xpb)[(size_t)nodeB * 8 + l] = pk;
            float v0 = axB * av0.x + ayB * av0.y + azB * av0.z + awB * av0.w;
            float v1 = axB * av1.x + ayB * av1.y + azB * av1.z + awB * av1.w;
#pragma unroll
            for (int m = 4; m >= 1; m >>= 1) {
                v0 += __shfl_xor(v0, m);
                v1 += __shfl_xor(v1, m);
            }
            if (l == 0) { s0[nodeB] = v0; s1[nodeB] = v1; }
        }
    }
}

// K2: edge pass — R10-validated configuration: EB=4096, 512 threads
// (8 waves), PT=8, 391 blocks, 32 KB staging, DENSITY 16 (load-bearing:
// R11's density-8 variant regressed +6us via partial-line write-amp).
// LDS-staged counting sort -> one global claim per touched bucket ->
// coalesced per-bucket-run copy-out. min/max -> private mm[bid] slot.
__global__ __launch_bounds__(512) void k_edge(const int* __restrict__ row,
                                              const int* __restrict__ col,
                                              const float* __restrict__ s0,
                                              const float* __restrict__ s1,
                                              int* __restrict__ gcount,
                                              int2* __restrict__ mm,
                                              uint2* __restrict__ gEdges) {
    __shared__ uint2 rec[EB];       // 32 KB staging
    __shared__ int hist[NB];        // 1 KB
    __shared__ int off[NB + 1];     // 1 KB: staging layout
    __shared__ int lcur[NB];        // 1 KB: staging cursors
    __shared__ int gbase[NB];       // 1 KB: claimed global bases
    __shared__ int wse[4];
    __shared__ int smn[8], smx[8];
    const int tid = threadIdx.x;
    if (tid < NB) hist[tid] = 0;
    __syncthreads();
    const int base = blockIdx.x * EB;
    unsigned px[PT];  // (b:8 | lr:8 | col:16)
    float    fa[PT];  // leaky-relu'd score
    int cnt = 0;
    int kmin = 0x7fffffff, kmax = 0x80000000;
    if (base + EB <= N_EDGES) {   // full block: int4 vector loads
#pragma unroll
        for (int i = 0; i < PT / 4; ++i) {
            const int4 r4 = ((const int4*)(row + base))[tid + i * EBK];
            const int4 c4 = ((const int4*)(col + base))[tid + i * EBK];
            const int rr[4] = {r4.x, r4.y, r4.z, r4.w};
            const int cc[4] = {c4.x, c4.y, c4.z, c4.w};
#pragma unroll
            for (int j = 0; j < 4; ++j) {
                const int r = rr[j];
                const int c = cc[j];
                float a = s0[r] + s1[c];
                a = a > 0.f ? a : ALPHA * a;
                const int k = enc_f(a);
                kmin = min(kmin, k);
                kmax = max(kmax, k);
                const unsigned b = (unsigned)r / RPB;
                const unsigned lr = (unsigned)r - b * RPB;
                px[cnt] = (b << 24) | (lr << 16) | (unsigned)c;
                fa[cnt] = a;
                ++cnt;
                atomicAdd(&hist[b], 1);
            }
        }
    } else {                      // tail block: scalar guarded
#pragma unroll
        for (int i = 0; i < PT; ++i) {
            const int e = base + i * EBK + tid;
            if (e >= N_EDGES) break;
            const int r = row[e];
            const int c = col[e];
            float a = s0[r] + s1[c];
            a = a > 0.f ? a : ALPHA * a;
            const int k = enc_f(a);
            kmin = min(kmin, k);
            kmax = max(kmax, k);
            const unsigned b = (unsigned)r / RPB;
            const unsigned lr = (unsigned)r - b * RPB;
            px[cnt] = (b << 24) | (lr << 16) | (unsigned)c;
            fa[cnt] = a;
            ++cnt;
            atomicAdd(&hist[b], 1);
        }
    }
    __syncthreads();
    // claim one contiguous global range per touched bucket (overlaps scan);
    // parallel exclusive scan of hist on the first 4 waves
    int h = 0, inc = 0;
    if (tid < NB) {
        h = hist[tid];
        gbase[tid] = h > 0 ? atomicAdd(&gcount[tid << 4], h) : 0;
        inc = h;
        const int lane = tid & 63;
#pragma unroll
        for (int d = 1; d < 64; d <<= 1) {
            const int u = __shfl_up(inc, d);
            if (lane >= d) inc += u;
        }
        if (lane == 63) wse[tid >> 6] = inc;
    }
    __syncthreads();
    if (tid < NB) {
        int addp = 0;
        const int wv = tid >> 6;
#pragma unroll
        for (int w = 0; w < 4; ++w)
            if (w < wv) addp += wse[w];
        const int exc = inc - h + addp;
        off[tid] = exc;
        lcur[tid] = exc;
        if (tid == NB - 1) off[NB] = inc + addp;
    }
    __syncthreads();
    // counting-sort scatter into LDS staging (bucket-contiguous)
    for (int j = 0; j < cnt; ++j) {
        const unsigned b = px[j] >> 24;
        const int p = atomicAdd(&lcur[b], 1);
        rec[p] = make_uint2(px[j], (unsigned)__float_as_int(fa[j]));
    }
    __syncthreads();
    // coalesced copy-out: consecutive i -> same-bucket run -> burst stores
    const int total = off[NB];
    for (int i = tid; i < total; i += EBK) {
        const uint2 e = rec[i];
        const unsigned b = e.x >> 24;
        const int pos = gbase[b] + (i - off[b]);
        if (pos < CAP) gEdges[(size_t)b * CAP + pos] = e;
    }
    // epilogue: block min/max -> private slot (no contended atomics)
#pragma unroll
    for (int m = 32; m >= 1; m >>= 1) {
        kmin = min(kmin, __shfl_xor(kmin, m));
        kmax = max(kmax, __shfl_xor(kmax, m));
    }
    const int wave = tid >> 6;
    if ((tid & 63) == 0) { smn[wave] = kmin; smx[wave] = kmax; }
    __syncthreads();
    if (tid == 0) {
#pragma unroll
        for (int w = 1; w < 8; ++w) {
            kmin = min(kmin, smn[w]);
            kmax = max(kmax, smx[w]);
        }
        mm[blockIdx.x] = make_int2(kmin, kmax);
    }
}

// K3: one 1024-thread block per FULL coarse bucket (256 blocks, ~51 KB LDS).
// v2: gEdges read ONCE into registers (<=8 records/thread, statically
// unrolled -> stays in VGPRs, no scratch). The old two-pass structure
// (hist pass + scatter pass) streamed the 12.8 MB record array twice; at
// 1 block/CU every saved cycle lands 1:1 on dur.
// prologue: reduce the 391-entry per-edge-block minmax table;
// hist:     from registers into 196 LDS bins;
// scan:     parallel 4-wave shfl prefix;
// scatter:  from registers, exp(minmaxnorm(score)) computed once;
// rows:     64 row-processors x 16 lanes (2 bf16 dims per lane via one u32
//           load), 4-way unrolled register accumulators, float2 out.
__global__ __launch_bounds__(1024, 1) void k_bucket(const int* __restrict__ gcount,
                                                    const uint2* __restrict__ gEdges,
                                                    const unsigned short* __restrict__ Xpb,
                                                    const int2* __restrict__ mm,
                                                    float* __restrict__ out) {
    __shared__ unsigned short scol[CAP]; // 16 KB
    __shared__ float swt[CAP];           // 32 KB
    __shared__ int off[RPB + 1];
    __shared__ int cur[RPB];
    __shared__ int wsc[4];
    __shared__ int rmn[16], rmx[16];
    __shared__ float s_mn, s_inv;
    const int b = blockIdx.x;
    const int t = threadIdx.x;
    const int cnt = min(gcount[b << 4], CAP);   // padded gcount
    const uint2* eb = gEdges + (size_t)b * CAP;

    // prologue: global min/max from the per-edge-block table
    int kmn = 0x7fffffff, kmx = 0x80000000;
    for (int i = t; i < NEB; i += 1024) {
        const int2 v = mm[i];
        kmn = min(kmn, v.x);
        kmx = max(kmx, v.y);
    }
#pragma unroll
    for (int m = 32; m >= 1; m >>= 1) {
        kmn = min(kmn, __shfl_xor(kmn, m));
        kmx = max(kmx, __shfl_xor(kmx, m));
    }
    if ((t & 63) == 0) { rmn[t >> 6] = kmn; rmx[t >> 6] = kmx; }
    if (t < RPB) cur[t] = 0;  // temp hist (same barrier covers this)
    __syncthreads();
    if (t == 0) {
#pragma unroll
        for (int w = 1; w < 16; ++w) {
            kmn = min(kmn, rmn[w]);
            kmx = max(kmx, rmx[w]);
        }
        const float mn = dec_f(kmn);
        const float mx = dec_f(kmx);
        s_mn = mn;
        s_inv = 1.0f / (mx - mn);
    }
    // single gEdges read into registers + histogram (static unroll: r[k]
    // is compile-time indexed -> VGPRs, not scratch)
    uint2 r0, r1, r2, r3, r4, r5, r6, r7;
#define RD(k, rk)                                            \
    {                                                        \
        const int i = t + (k << 10);                         \
        if (i < cnt) {                                       \
            rk = eb[i];                                      \
            atomicAdd(&cur[(rk.x >> 16) & 0xFFu], 1);        \
        }                                                    \
    }
    RD(0, r0) RD(1, r1) RD(2, r2) RD(3, r3)
    RD(4, r4) RD(5, r5) RD(6, r6) RD(7, r7)
#undef RD
    __syncthreads();
    // parallel exclusive scan of cur[0..195] -> off (first 4 waves)
    int inc_s = 0, v_s = 0;
    if (t < 256) {
        v_s = (t < RPB) ? cur[t] : 0;
        inc_s = v_s;
        const int lane = t & 63;
#pragma unroll
        for (int d = 1; d < 64; d <<= 1) {
            const int u = __shfl_up(inc_s, d);
            if (lane >= d) inc_s += u;
        }
        if (lane == 63) wsc[t >> 6] = inc_s;
    }
    __syncthreads();
    if (t < 256) {
        int addp = 0;
        const int wv = t >> 6;
#pragma unroll
        for (int w = 0; w < 4; ++w)
            if (w < wv) addp += wsc[w];
        if (t < RPB) off[t] = inc_s - v_s + addp;
        if (t == 255) off[RPB] = inc_s + addp;
    }
    __syncthreads();
    if (t < RPB) cur[t] = off[t];
    __syncthreads();
    const float mn = s_mn;
    const float inv = s_inv;
    // scatter from registers (no second gEdges pass)
#define SC(k, rk)                                                         \
    {                                                                     \
        const int i = t + (k << 10);                                      \
        if (i < cnt) {                                                    \
            const int lr = (int)((rk.x >> 16) & 0xFFu);                   \
            const int p = atomicAdd(&cur[lr], 1);                         \
            if (p < CAP) {                                                \
                scol[p] = (unsigned short)(rk.x & 0xFFFFu);               \
                swt[p] = __expf((__int_as_float(rk.y) - mn) * inv);       \
            }                                                             \
        }                                                                 \
    }
    SC(0, r0) SC(1, r1) SC(2, r2) SC(3, r3)
    SC(4, r4) SC(5, r5) SC(6, r6) SC(7, r7)
#undef SC
    __syncthreads();

    // row processing: 64 processors x 16 lanes, 2 dims/lane, 4-way unroll
    const int proc = t >> 4;  // 0..63
    const int d2 = t & 15;    // dims [2*d2, 2*d2+1]
    const unsigned* Xp32 = (const unsigned*)Xpb;
    for (int lr = proc; lr < RPB; lr += 64) {
        const int s = off[lr];
        const int e2 = off[lr + 1];
        float pa0 = 0.f, pa1 = 0.f, pa2 = 0.f, pa3 = 0.f;
        float pb0 = 0.f, pb1 = 0.f, pb2 = 0.f, pb3 = 0.f;
        float w0s = 0.f, w1s = 0.f, w2s = 0.f, w3s = 0.f;
        int i = s;
        for (; i + 3 < e2; i += 4) {
            const int c0 = scol[i];
            const int c1 = scol[i + 1];
            const int c2 = scol[i + 2];
            const int c3 = scol[i + 3];
            const float w0 = swt[i];
            const float w1 = swt[i + 1];
            const float w2 = swt[i + 2];
            const float w3 = swt[i + 3];
            const unsigned u0 = Xp32[(size_t)c0 * 16 + d2];
            const unsigned u1 = Xp32[(size_t)c1 * 16 + d2];
            const unsigned u2 = Xp32[(size_t)c2 * 16 + d2];
            const unsigned u3 = Xp32[(size_t)c3 * 16 + d2];
            pa0 += w0 * bf2f((unsigned short)(u0 & 0xFFFFu));
            pb0 += w0 * bf2f((unsigned short)(u0 >> 16));
            pa1 += w1 * bf2f((unsigned short)(u1 & 0xFFFFu));
            pb1 += w1 * bf2f((unsigned short)(u1 >> 16));
            pa2 += w2 * bf2f((unsigned short)(u2 & 0xFFFFu));
            pb2 += w2 * bf2f((unsigned short)(u2 >> 16));
            pa3 += w3 * bf2f((unsigned short)(u3 & 0xFFFFu));
            pb3 += w3 * bf2f((unsigned short)(u3 >> 16));
            w0s += w0; w1s += w1; w2s += w2; w3s += w3;
        }
        for (; i < e2; ++i) {
            const float w = swt[i];
            const unsigned u = Xp32[(size_t)scol[i] * 16 + d2];
            pa0 += w * bf2f((unsigned short)(u & 0xFFFFu));
            pb0 += w * bf2f((unsigned short)(u >> 16));
            w0s += w;
        }
        const int r = b * RPB + lr;
        if (r < N_NODES) {
            const float ws = w0s + w1s + w2s + w3s;
            float2 o;
            o.x = (pa0 + pa1 + pa2 + pa3) / ws;
            o.y = (pb0 + pb1 + pb2 + pb3) / ws;
            ((float2*)out)[(size_t)r * 16 + d2] = o;
        }
    }
}

extern "C" void kernel_launch(void* const* d_in, const int* in_sizes, int n_in,
                              void* d_out, int out_size, void* d_ws, size_t ws_size,
                              hipStream_t stream) {
    const float* X  = (const float*)d_in[0];
    const float* W  = (const float*)d_in[1];
    const float* a0 = (const float*)d_in[2];
    const float* a1 = (const float*)d_in[3];
    const int* row  = (const int*)d_in[4];
    const int* col  = (const int*)d_in[5];
    float* out = (float*)d_out;

    // Workspace layout (4B units):
    // [pad: 64][gcount padded: NB*GST = 4096][mm: 2048]
    // [s0: 50048][s1: 50048][Xpb: 800000 u32][gEdges: NB*CAP uint2] ~20.4 MB
    float* ws = (float*)d_ws;
    int*   gcount = (int*)ws + 64;
    int2*  mm = (int2*)((int*)ws + 64 + NB * GST);
    float* s0 = ws + 64 + NB * GST + 2048;
    float* s1 = s0 + 50048;
    unsigned short* Xpb = (unsigned short*)(s1 + 50048);
    uint2* gEdges = (uint2*)(s1 + 50048 + 800000);

    k_gemm<<<NXB, 256, 0, stream>>>(X, W, a0, a1, Xpb, s0, s1, gcount);
    k_edge<<<NEB, 512, 0, stream>>>(row, col, s0, s1, gcount, mm, gEdges);
    k_bucket<<<NB, 1024, 0, stream>>>(gcount, gEdges, Xpb, mm, out);
}